// Round 3
// baseline (133.786 us; speedup 1.0000x reference)
//
#include <hip/hip_runtime.h>
#include <hip/hip_bf16.h>
#include <math.h>

typedef __attribute__((ext_vector_type(8))) short bf16x8;
typedef __attribute__((ext_vector_type(4))) float f32x4;
typedef __attribute__((ext_vector_type(2))) float f32x2;

constexpr int B_ = 4096;
constexpr int N_ = 8192;   // 2B rows
constexpr int D_ = 128;
constexpr float INV_T = 2.0f;              // 1/temperature
constexpr float E2C = 7.38905609893065f;   // exp(2) — diagonal self-sim term

// ------- Kernel A: normalize pair -> bf16 Z rows p & p+B, pos[p], zero denom -
// One wave per pair p: loads both fp32 rows (8B/lane), 3 fused shfl-reductions
// (|ei|^2, |ej|^2, <ei,ej>), writes both unit bf16 rows + fp32 positives.
__global__ __launch_bounds__(256) void nrm_kernel(const float* __restrict__ ei,
                                                  const float* __restrict__ ej,
                                                  __hip_bfloat16* __restrict__ zb,
                                                  float* __restrict__ pos,
                                                  float* __restrict__ denom,
                                                  float* __restrict__ out) {
    int p    = (blockIdx.x * blockDim.x + threadIdx.x) >> 6;  // pair id
    int lane = threadIdx.x & 63;
    if (p >= B_) return;
    f32x2 a = *(const f32x2*)(ei + (size_t)p * D_ + lane * 2);
    f32x2 b = *(const f32x2*)(ej + (size_t)p * D_ + lane * 2);
    float na = a.x * a.x + a.y * a.y;
    float nb = b.x * b.x + b.y * b.y;
    float dt = a.x * b.x + a.y * b.y;
    #pragma unroll
    for (int m = 1; m < 64; m <<= 1) {
        na += __shfl_xor(na, m);
        nb += __shfl_xor(nb, m);
        dt += __shfl_xor(dt, m);
    }
    float ra = rsqrtf(na), rb = rsqrtf(nb);
    __hip_bfloat162 oa, ob;
    oa.x = __float2bfloat16(a.x * ra); oa.y = __float2bfloat16(a.y * ra);
    ob.x = __float2bfloat16(b.x * rb); ob.y = __float2bfloat16(b.y * rb);
    *(__hip_bfloat162*)(zb + (size_t)p * D_ + lane * 2)        = oa;
    *(__hip_bfloat162*)(zb + (size_t)(p + B_) * D_ + lane * 2) = ob;
    if (lane == 0) {
        pos[p] = dt * ra * rb;
        denom[p] = 0.0f;
        denom[p + B_] = 0.0f;
        if (p == 0) out[0] = 0.0f;
    }
}

// ------- Kernel B: fused sim = Z Z^T, exp(2*sim), row sums -------------------
// Block: 4 waves, each owns 32 rows (2 m-tiles). Per iter each wave processes a
// 32x32 output tile: 8 independent 16B B-loads in flight, 16 MFMA, 16 exp.
// Grid: 64 row-blocks x NJ=32 column splits = 2048 blocks. No LDS, no barriers;
// Z (2 MB) is L2-resident on every XCD.
constexpr int NJ = 32;
constexpr int BLK_ROWS = 128;
constexpr int JCHUNK = N_ / NJ;  // 256 columns per block

__global__ __launch_bounds__(256, 4) void simsum_kernel(const __hip_bfloat16* __restrict__ zb,
                                                        float* __restrict__ denom) {
    int lane = threadIdx.x & 63;
    int wave = threadIdx.x >> 6;                       // 0..3
    int r0   = blockIdx.x * BLK_ROWS + wave * 32;      // wave's first row
    int jbase = blockIdx.y * JCHUNK;
    int g  = lane >> 4;                                // k-group 0..3
    int lm = lane & 15;

    const short* Z = (const short*)zb;

    // A fragments: rows r0 + t*16 + lm, k = s*32 + g*8 .. +8  (16B each)
    bf16x8 a[2][4];
    #pragma unroll
    for (int t = 0; t < 2; ++t)
        #pragma unroll
        for (int s = 0; s < 4; ++s)
            a[t][s] = *(const bf16x8*)(Z + (size_t)(r0 + t * 16 + lm) * D_ + s * 32 + g * 8);

    f32x4 rs0 = {0.f, 0.f, 0.f, 0.f};
    f32x4 rs1 = {0.f, 0.f, 0.f, 0.f};

    const short* pB = Z + (size_t)(jbase + lm) * D_ + g * 8;
    #pragma unroll 1
    for (int jt = 0; jt < JCHUNK / 32; ++jt) {
        const short* p0 = pB;             // columns j0 .. j0+15
        const short* p1 = pB + 16 * D_;   // columns j0+16 .. j0+31
        bf16x8 b00 = *(const bf16x8*)(p0);
        bf16x8 b01 = *(const bf16x8*)(p0 + 32);
        bf16x8 b02 = *(const bf16x8*)(p0 + 64);
        bf16x8 b03 = *(const bf16x8*)(p0 + 96);
        bf16x8 b10 = *(const bf16x8*)(p1);
        bf16x8 b11 = *(const bf16x8*)(p1 + 32);
        bf16x8 b12 = *(const bf16x8*)(p1 + 64);
        bf16x8 b13 = *(const bf16x8*)(p1 + 96);
        f32x4 acc00 = {0.f, 0.f, 0.f, 0.f};
        f32x4 acc01 = {0.f, 0.f, 0.f, 0.f};
        f32x4 acc10 = {0.f, 0.f, 0.f, 0.f};
        f32x4 acc11 = {0.f, 0.f, 0.f, 0.f};
        acc00 = __builtin_amdgcn_mfma_f32_16x16x32_bf16(a[0][0], b00, acc00, 0, 0, 0);
        acc10 = __builtin_amdgcn_mfma_f32_16x16x32_bf16(a[1][0], b00, acc10, 0, 0, 0);
        acc01 = __builtin_amdgcn_mfma_f32_16x16x32_bf16(a[0][0], b10, acc01, 0, 0, 0);
        acc11 = __builtin_amdgcn_mfma_f32_16x16x32_bf16(a[1][0], b10, acc11, 0, 0, 0);
        acc00 = __builtin_amdgcn_mfma_f32_16x16x32_bf16(a[0][1], b01, acc00, 0, 0, 0);
        acc10 = __builtin_amdgcn_mfma_f32_16x16x32_bf16(a[1][1], b01, acc10, 0, 0, 0);
        acc01 = __builtin_amdgcn_mfma_f32_16x16x32_bf16(a[0][1], b11, acc01, 0, 0, 0);
        acc11 = __builtin_amdgcn_mfma_f32_16x16x32_bf16(a[1][1], b11, acc11, 0, 0, 0);
        acc00 = __builtin_amdgcn_mfma_f32_16x16x32_bf16(a[0][2], b02, acc00, 0, 0, 0);
        acc10 = __builtin_amdgcn_mfma_f32_16x16x32_bf16(a[1][2], b02, acc10, 0, 0, 0);
        acc01 = __builtin_amdgcn_mfma_f32_16x16x32_bf16(a[0][2], b12, acc01, 0, 0, 0);
        acc11 = __builtin_amdgcn_mfma_f32_16x16x32_bf16(a[1][2], b12, acc11, 0, 0, 0);
        acc00 = __builtin_amdgcn_mfma_f32_16x16x32_bf16(a[0][3], b03, acc00, 0, 0, 0);
        acc10 = __builtin_amdgcn_mfma_f32_16x16x32_bf16(a[1][3], b03, acc10, 0, 0, 0);
        acc01 = __builtin_amdgcn_mfma_f32_16x16x32_bf16(a[0][3], b13, acc01, 0, 0, 0);
        acc11 = __builtin_amdgcn_mfma_f32_16x16x32_bf16(a[1][3], b13, acc11, 0, 0, 0);
        #pragma unroll
        for (int r = 0; r < 4; ++r) {
            rs0[r] += __expf(INV_T * acc00[r]) + __expf(INV_T * acc01[r]);
            rs1[r] += __expf(INV_T * acc10[r]) + __expf(INV_T * acc11[r]);
        }
        pB += 32 * D_;
    }

    // reduce partial row sums across the 16 column-lanes (low 4 lane bits)
    #pragma unroll
    for (int m = 1; m < 16; m <<= 1) {
        #pragma unroll
        for (int r = 0; r < 4; ++r) {
            rs0[r] += __shfl_xor(rs0[r], m);
            rs1[r] += __shfl_xor(rs1[r], m);
        }
    }
    if (lm == 0) {
        #pragma unroll
        for (int r = 0; r < 4; ++r) {
            atomicAdd(&denom[r0 + g * 4 + r],      rs0[r]);
            atomicAdd(&denom[r0 + 16 + g * 4 + r], rs1[r]);
        }
    }
}

// ------- Kernel C: loss = mean(log(denom - e^2) - 2*pos) ---------------------
__global__ __launch_bounds__(256) void loss_kernel(const float* __restrict__ denom,
                                                   const float* __restrict__ pos,
                                                   float* __restrict__ out) {
    int tid = threadIdx.x;
    int k   = blockIdx.x * 256 + tid;
    float d = denom[k] - E2C;
    float v = __logf(d) - pos[k & (B_ - 1)] * INV_T;
    #pragma unroll
    for (int m = 1; m < 64; m <<= 1) v += __shfl_xor(v, m);
    __shared__ float part[4];
    if ((tid & 63) == 0) part[tid >> 6] = v;
    __syncthreads();
    if (tid == 0)
        atomicAdd(out, (part[0] + part[1] + part[2] + part[3]) * (1.0f / N_));
}

// ------- launch --------------------------------------------------------------
extern "C" void kernel_launch(void* const* d_in, const int* in_sizes, int n_in,
                              void* d_out, int out_size, void* d_ws, size_t ws_size,
                              hipStream_t stream) {
    const float* ei = (const float*)d_in[0];
    const float* ej = (const float*)d_in[1];
    float* out = (float*)d_out;

    __hip_bfloat16* zb = (__hip_bfloat16*)d_ws;                    // 2 MB
    float* denom = (float*)((char*)d_ws + (size_t)N_ * D_ * 2);    // 32 KB
    float* pos   = denom + N_;                                     // 16 KB

    nrm_kernel<<<dim3(B_ / 4), dim3(256), 0, stream>>>(ei, ej, zb, pos, denom, out);
    simsum_kernel<<<dim3(N_ / BLK_ROWS, NJ), dim3(256), 0, stream>>>(zb, denom);
    loss_kernel<<<dim3(N_ / 256), dim3(256), 0, stream>>>(denom, pos, out);
}

// Round 6
// 130.429 us; speedup vs baseline: 1.0257x; 1.0257x over previous
//
#include <hip/hip_runtime.h>
#include <hip/hip_bf16.h>
#include <math.h>

typedef __attribute__((ext_vector_type(8))) short bf16x8;
typedef __attribute__((ext_vector_type(4))) float f32x4;
typedef __attribute__((ext_vector_type(2))) float f32x2;

constexpr int B_ = 4096;
constexpr int N_ = 8192;   // 2B rows
constexpr int D_ = 128;
constexpr float INV_T = 2.0f;              // 1/temperature
constexpr float E2C = 7.38905609893065f;   // exp(2) — diagonal self-sim term

// ------- Kernel A: normalize pair -> bf16 Z rows p & p+B, pos[p] -------------
__global__ __launch_bounds__(256) void nrm_kernel(const float* __restrict__ ei,
                                                  const float* __restrict__ ej,
                                                  __hip_bfloat16* __restrict__ zb,
                                                  float* __restrict__ pos,
                                                  float* __restrict__ out) {
    int p    = (blockIdx.x * blockDim.x + threadIdx.x) >> 6;  // pair id
    int lane = threadIdx.x & 63;
    if (p >= B_) return;
    f32x2 a = *(const f32x2*)(ei + (size_t)p * D_ + lane * 2);
    f32x2 b = *(const f32x2*)(ej + (size_t)p * D_ + lane * 2);
    float na = a.x * a.x + a.y * a.y;
    float nb = b.x * b.x + b.y * b.y;
    float dt = a.x * b.x + a.y * b.y;
    #pragma unroll
    for (int m = 1; m < 64; m <<= 1) {
        na += __shfl_xor(na, m);
        nb += __shfl_xor(nb, m);
        dt += __shfl_xor(dt, m);
    }
    float ra = rsqrtf(na), rb = rsqrtf(nb);
    __hip_bfloat162 oa, ob;
    oa.x = __float2bfloat16(a.x * ra); oa.y = __float2bfloat16(a.y * ra);
    ob.x = __float2bfloat16(b.x * rb); ob.y = __float2bfloat16(b.y * rb);
    *(__hip_bfloat162*)(zb + (size_t)p * D_ + lane * 2)        = oa;
    *(__hip_bfloat162*)(zb + (size_t)(p + B_) * D_ + lane * 2) = ob;
    if (lane == 0) {
        pos[p] = dt * ra * rb;
        if (p == 0) out[0] = 0.0f;
    }
}

// ------- Kernel B: fused sim = Z Z^T, exp(2*sim), partial row sums -----------
// Block: 4 waves, each owns 32 rows (2 m-tiles of 16). Grid: 64 row-blocks x
// NJ=32 column splits. Per wave: 16 subtiles of 16 columns, DEPTH-2 register
// prefetch (3 rotating B-buffers, fully unrolled -> static indices, counted
// vmcnt keeps 8 loads in flight over ~400cy of MFMA+exp). No LDS, no barriers,
// no atomics: each wave writes its 32 partial sums to a unique (jsplit,row).
constexpr int NJ = 32;
constexpr int BLK_ROWS = 128;
constexpr int JCHUNK = N_ / NJ;      // 256 columns per block
constexpr int NT = JCHUNK / 16;      // 16 subtiles

__global__ __launch_bounds__(256) void simsum_kernel(const __hip_bfloat16* __restrict__ zb,
                                                     float* __restrict__ part) {
    int lane = threadIdx.x & 63;
    int wave = threadIdx.x >> 6;                       // 0..3
    int r0   = blockIdx.x * BLK_ROWS + wave * 32;      // wave's first row
    int jbase = blockIdx.y * JCHUNK;
    int g  = lane >> 4;                                // k-group 0..3
    int lm = lane & 15;

    const short* Z = (const short*)zb;

    // A fragments: rows r0 + t*16 + lm, k = s*32 + g*8 .. +8  (16B each)
    bf16x8 a[2][4];
    #pragma unroll
    for (int t = 0; t < 2; ++t)
        #pragma unroll
        for (int s = 0; s < 4; ++s)
            a[t][s] = *(const bf16x8*)(Z + (size_t)(r0 + t * 16 + lm) * D_ + s * 32 + g * 8);

    f32x4 rs0 = {0.f, 0.f, 0.f, 0.f};
    f32x4 rs1 = {0.f, 0.f, 0.f, 0.f};

    const short* colbase = Z + (size_t)(jbase + lm) * D_ + g * 8;

    // 3-stage rotating register buffers, depth-2 prefetch
    bf16x8 b[3][4];
    #pragma unroll
    for (int s = 0; s < 4; ++s) b[0][s] = *(const bf16x8*)(colbase + 0 * 16 * D_ + s * 32);
    #pragma unroll
    for (int s = 0; s < 4; ++s) b[1][s] = *(const bf16x8*)(colbase + 1 * 16 * D_ + s * 32);

    #pragma unroll
    for (int jt = 0; jt < NT; ++jt) {
        if (jt + 2 < NT) {               // compile-time under full unroll
            #pragma unroll
            for (int s = 0; s < 4; ++s)
                b[(jt + 2) % 3][s] = *(const bf16x8*)(colbase + (jt + 2) * 16 * D_ + s * 32);
        }
        f32x4 acc0 = {0.f, 0.f, 0.f, 0.f};
        f32x4 acc1 = {0.f, 0.f, 0.f, 0.f};
        #pragma unroll
        for (int s = 0; s < 4; ++s) {
            acc0 = __builtin_amdgcn_mfma_f32_16x16x32_bf16(a[0][s], b[jt % 3][s], acc0, 0, 0, 0);
            acc1 = __builtin_amdgcn_mfma_f32_16x16x32_bf16(a[1][s], b[jt % 3][s], acc1, 0, 0, 0);
        }
        #pragma unroll
        for (int r = 0; r < 4; ++r) {
            rs0[r] += __expf(INV_T * acc0[r]);
            rs1[r] += __expf(INV_T * acc1[r]);
        }
    }

    // reduce partial row sums across the 16 column-lanes (low 4 lane bits)
    #pragma unroll
    for (int m = 1; m < 16; m <<= 1) {
        #pragma unroll
        for (int r = 0; r < 4; ++r) {
            rs0[r] += __shfl_xor(rs0[r], m);
            rs1[r] += __shfl_xor(rs1[r], m);
        }
    }
    // non-atomic partial-sum write: slot (blockIdx.y, row) owned by this wave
    if (lm == 0) {
        float* pr = part + (size_t)blockIdx.y * N_ + r0;
        #pragma unroll
        for (int r = 0; r < 4; ++r) {
            pr[g * 4 + r]      = rs0[r];
            pr[16 + g * 4 + r] = rs1[r];
        }
    }
}

// ------- Kernel C: loss = mean(log(sum_c part[c][k] - e^2) - 2*pos) ----------
__global__ __launch_bounds__(256) void loss_kernel(const float* __restrict__ part,
                                                   const float* __restrict__ pos,
                                                   float* __restrict__ out) {
    int tid = threadIdx.x;
    int k   = blockIdx.x * 256 + tid;
    float d = 0.0f;
    #pragma unroll
    for (int c = 0; c < NJ; ++c) d += part[(size_t)c * N_ + k];
    d -= E2C;
    float v = __logf(d) - pos[k & (B_ - 1)] * INV_T;
    #pragma unroll
    for (int m = 1; m < 64; m <<= 1) v += __shfl_xor(v, m);
    __shared__ float ps[4];
    if ((tid & 63) == 0) ps[tid >> 6] = v;
    __syncthreads();
    if (tid == 0)
        atomicAdd(out, (ps[0] + ps[1] + ps[2] + ps[3]) * (1.0f / N_));
}

// ------- launch --------------------------------------------------------------
extern "C" void kernel_launch(void* const* d_in, const int* in_sizes, int n_in,
                              void* d_out, int out_size, void* d_ws, size_t ws_size,
                              hipStream_t stream) {
    const float* ei = (const float*)d_in[0];
    const float* ej = (const float*)d_in[1];
    float* out = (float*)d_out;

    __hip_bfloat16* zb = (__hip_bfloat16*)d_ws;                       // 2 MB
    float* pos  = (float*)((char*)d_ws + (size_t)N_ * D_ * 2);        // 16 KB
    float* part = pos + B_;                                           // NJ*N_*4 = 1 MB

    nrm_kernel<<<dim3(B_ / 4), dim3(256), 0, stream>>>(ei, ej, zb, pos, out);
    simsum_kernel<<<dim3(N_ / BLK_ROWS, NJ), dim3(256), 0, stream>>>(zb, part);
    loss_kernel<<<dim3(N_ / 256), dim3(256), 0, stream>>>(part, pos, out);
}

// Round 9
// 96.997 us; speedup vs baseline: 1.3793x; 1.3447x over previous
//
#include <hip/hip_runtime.h>
#include <hip/hip_bf16.h>
#include <math.h>

typedef __attribute__((ext_vector_type(8))) short bf16x8;
typedef __attribute__((ext_vector_type(4))) float f32x4;
typedef __attribute__((ext_vector_type(2))) float f32x2;

constexpr int B_ = 4096;
constexpr int N_ = 8192;   // 2B rows
constexpr int D_ = 128;
constexpr float INV_T = 2.0f;              // 1/temperature
constexpr float EXP2C = 2.0f * 1.4426950408889634f;  // (1/T)*log2(e) for exp2
constexpr float E2C = 7.38905609893065f;   // exp(2) — diagonal self-sim term

// ZF fragment-major layout: row j, element e  ->  short index
//   (j>>4)*2048 + (e>>3)*128 + (j&15)*8 + (e&7)
// so a wave's MFMA fragment load (panel p, k-slice s, lane) is the contiguous
// 1KB block at  p*2048 + s*512 + lane*8  (lane i exactly at byte i*16).

// ------- Kernel A: normalize pair -> ZF rows p & p+B, pos[p] -----------------
__global__ __launch_bounds__(256) void nrm_kernel(const float* __restrict__ ei,
                                                  const float* __restrict__ ej,
                                                  short* __restrict__ zf,
                                                  float* __restrict__ pos,
                                                  float* __restrict__ out) {
    int p    = (blockIdx.x * blockDim.x + threadIdx.x) >> 6;  // pair id
    int lane = threadIdx.x & 63;
    if (p >= B_) return;
    f32x2 a = *(const f32x2*)(ei + (size_t)p * D_ + lane * 2);
    f32x2 b = *(const f32x2*)(ej + (size_t)p * D_ + lane * 2);
    float na = a.x * a.x + a.y * a.y;
    float nb = b.x * b.x + b.y * b.y;
    float dt = a.x * b.x + a.y * b.y;
    #pragma unroll
    for (int m = 1; m < 64; m <<= 1) {
        na += __shfl_xor(na, m);
        nb += __shfl_xor(nb, m);
        dt += __shfl_xor(dt, m);
    }
    float ra = rsqrtf(na), rb = rsqrtf(nb);
    __hip_bfloat162 oa, ob;
    oa.x = __float2bfloat16(a.x * ra); oa.y = __float2bfloat16(a.y * ra);
    ob.x = __float2bfloat16(b.x * rb); ob.y = __float2bfloat16(b.y * rb);
    // elements e=2*lane, 2*lane+1  ->  idx = (j>>4)*2048 + (lane>>2)*128 + (j&15)*8 + (lane&3)*2
    size_t fi = (size_t)(lane >> 2) * 128 + (p & 15) * 8 + (lane & 3) * 2;
    *(__hip_bfloat162*)(zf + (size_t)(p >> 4) * 2048 + fi)          = oa;
    *(__hip_bfloat162*)(zf + (size_t)((p + B_) >> 4) * 2048 + fi)   = ob;
    if (lane == 0) {
        pos[p] = dt * ra * rb;
        if (p == 0) out[0] = 0.0f;
    }
}

// ------- Kernel B: fused sim = ZF ZF^T, exp(2*sim), partial row sums ---------
// Block: 4 waves x 64 rows = 256 rows. Grid: 32 row-blocks x NJ=32 col splits.
// All loads are contiguous 1KB wave-loads (fragment-major layout): no scatter,
// no LDS, no barriers, no atomics. Depth-2 rotating register prefetch.
constexpr int NJ = 32;
constexpr int BLK_ROWS = 256;
constexpr int JCHUNK = N_ / NJ;      // 256 columns per block
constexpr int NT = JCHUNK / 16;      // 16 column-panels per wave

__global__ __launch_bounds__(256) void simsum_kernel(const short* __restrict__ zf,
                                                     float* __restrict__ part) {
    int lane = threadIdx.x & 63;
    int wave = threadIdx.x >> 6;                        // 0..3
    int r0   = blockIdx.x * BLK_ROWS + wave * 64;       // wave's first row
    int pr0  = r0 >> 4;                                 // first A panel (4 per wave)
    int pj0  = (blockIdx.y * JCHUNK) >> 4;              // first B panel
    int g  = lane >> 4;
    int lm = lane & 15;

    const short* ZA = zf + (size_t)pr0 * 2048 + lane * 8;
    const short* ZB = zf + (size_t)pj0 * 2048 + lane * 8;

    // A fragments: 4 panels x 4 k-slices, each a contiguous 1KB wave-load
    bf16x8 a[4][4];
    #pragma unroll
    for (int t = 0; t < 4; ++t)
        #pragma unroll
        for (int s = 0; s < 4; ++s)
            a[t][s] = *(const bf16x8*)(ZA + t * 2048 + s * 512);

    f32x4 rs[4];
    #pragma unroll
    for (int t = 0; t < 4; ++t) rs[t] = f32x4{0.f, 0.f, 0.f, 0.f};

    // 3-stage rotating register buffers, depth-2 prefetch (all static indices)
    bf16x8 b[3][4];
    #pragma unroll
    for (int s = 0; s < 4; ++s) b[0][s] = *(const bf16x8*)(ZB + 0 * 2048 + s * 512);
    #pragma unroll
    for (int s = 0; s < 4; ++s) b[1][s] = *(const bf16x8*)(ZB + 1 * 2048 + s * 512);

    #pragma unroll
    for (int jt = 0; jt < NT; ++jt) {
        if (jt + 2 < NT) {
            #pragma unroll
            for (int s = 0; s < 4; ++s)
                b[(jt + 2) % 3][s] = *(const bf16x8*)(ZB + (size_t)(jt + 2) * 2048 + s * 512);
        }
        f32x4 acc[4];
        #pragma unroll
        for (int t = 0; t < 4; ++t) acc[t] = f32x4{0.f, 0.f, 0.f, 0.f};
        #pragma unroll
        for (int s = 0; s < 4; ++s)
            #pragma unroll
            for (int t = 0; t < 4; ++t)
                acc[t] = __builtin_amdgcn_mfma_f32_16x16x32_bf16(a[t][s], b[jt % 3][s], acc[t], 0, 0, 0);
        #pragma unroll
        for (int t = 0; t < 4; ++t)
            #pragma unroll
            for (int r = 0; r < 4; ++r)
                rs[t][r] += exp2f(EXP2C * acc[t][r]);
    }

    // reduce partial row sums across the 16 column-lanes (low 4 lane bits)
    #pragma unroll
    for (int m = 1; m < 16; m <<= 1)
        #pragma unroll
        for (int t = 0; t < 4; ++t)
            #pragma unroll
            for (int r = 0; r < 4; ++r)
                rs[t][r] += __shfl_xor(rs[t][r], m);

    // non-atomic partial-sum write: slot (blockIdx.y, row) owned by this wave
    if (lm == 0) {
        float* pr = part + (size_t)blockIdx.y * N_ + r0;
        #pragma unroll
        for (int t = 0; t < 4; ++t)
            #pragma unroll
            for (int r = 0; r < 4; ++r)
                pr[t * 16 + g * 4 + r] = rs[t][r];
    }
}

// ------- Kernel C: loss = mean(log(sum_c part[c][k] - e^2) - 2*pos) ----------
__global__ __launch_bounds__(256) void loss_kernel(const float* __restrict__ part,
                                                   const float* __restrict__ pos,
                                                   float* __restrict__ out) {
    int tid = threadIdx.x;
    int k   = blockIdx.x * 256 + tid;
    float d = 0.0f;
    #pragma unroll
    for (int c = 0; c < NJ; ++c) d += part[(size_t)c * N_ + k];
    d -= E2C;
    float v = __logf(d) - pos[k & (B_ - 1)] * INV_T;
    #pragma unroll
    for (int m = 1; m < 64; m <<= 1) v += __shfl_xor(v, m);
    __shared__ float ps[4];
    if ((tid & 63) == 0) ps[tid >> 6] = v;
    __syncthreads();
    if (tid == 0)
        atomicAdd(out, (ps[0] + ps[1] + ps[2] + ps[3]) * (1.0f / N_));
}

// ------- launch --------------------------------------------------------------
extern "C" void kernel_launch(void* const* d_in, const int* in_sizes, int n_in,
                              void* d_out, int out_size, void* d_ws, size_t ws_size,
                              hipStream_t stream) {
    const float* ei = (const float*)d_in[0];
    const float* ej = (const float*)d_in[1];
    float* out = (float*)d_out;

    short* zf   = (short*)d_ws;                                       // 2 MB
    float* pos  = (float*)((char*)d_ws + (size_t)N_ * D_ * 2);        // 16 KB
    float* part = pos + B_;                                           // NJ*N_*4 = 1 MB

    nrm_kernel<<<dim3(B_ / 4), dim3(256), 0, stream>>>(ei, ej, zf, pos, out);
    simsum_kernel<<<dim3(N_ / BLK_ROWS, NJ), dim3(256), 0, stream>>>(zf, part);
    loss_kernel<<<dim3(N_ / 256), dim3(256), 0, stream>>>(part, pos, out);
}